// Round 8
// baseline (408.646 us; speedup 1.0000x reference)
//
#include <hip/hip_runtime.h>
#include <hip/hip_bf16.h>

typedef unsigned short u16;
typedef _Float16 h16;
typedef h16 h16x8 __attribute__((ext_vector_type(8)));
typedef h16 h16x4 __attribute__((ext_vector_type(4)));
typedef float f32x4 __attribute__((ext_vector_type(4)));

#define S_LEN 2048
#define QLR   1536
#define KVLR  512
#define NHEAD 16
#define QHD   192
#define QHS   200   // padded row stride for Qh/Kh
#define VDIM  128
#define SCALE 0.07216878364870322f   // 192^-0.5
#define FREQC (-0.4152410118609203f) // -log2(10000)/32

__device__ __forceinline__ void gld16(const h16* g, h16* l){
  __builtin_amdgcn_global_load_lds((__attribute__((address_space(1))) const void*)g,
                                   (__attribute__((address_space(3))) void*)l, 16, 0, 0);
}

// ---------- fp32 -> fp16 elementwise ----------
__global__ __launch_bounds__(256) void k_cvt(const float* __restrict__ in, h16* __restrict__ out, int n4){
  int i = blockIdx.x * 256 + threadIdx.x;
  if (i < n4){
    float4 v = ((const float4*)in)[i];
    h16x4 o = { (h16)v.x, (h16)v.y, (h16)v.z, (h16)v.w };
    ((h16x4*)out)[i] = o;
  }
}

// ---------- fp32 KxN -> fp16 NxK transpose (64x64 tiles) ----------
__global__ __launch_bounds__(256) void k_tc(const float* __restrict__ W, h16* __restrict__ WT, int K, int N){
  __shared__ float t[64][65];
  int k0 = blockIdx.y * 64, n0 = blockIdx.x * 64;
  int tid = threadIdx.x;
  int r = tid >> 4, c4 = (tid & 15) * 4;
#pragma unroll
  for (int it = 0; it < 4; it++){
    float4 v = *(const float4*)(W + (size_t)(k0 + it*16 + r) * N + n0 + c4);
    t[it*16+r][c4] = v.x; t[it*16+r][c4+1] = v.y; t[it*16+r][c4+2] = v.z; t[it*16+r][c4+3] = v.w;
  }
  __syncthreads();
  int n = tid >> 2, k16 = (tid & 3) * 16;
  h16x8 o0, o1;
#pragma unroll
  for (int e = 0; e < 8; e++){ o0[e] = (h16)t[k16 + e][n]; o1[e] = (h16)t[k16 + 8 + e][n]; }
  h16* dst = WT + (size_t)(n0 + n) * K + k0 + k16;
  *(h16x8*)dst = o0;
  *(h16x8*)(dst + 8) = o1;
}

// ---------- shared GEMM mainloop ----------
__device__ __forceinline__ void gemm_core(const h16* __restrict__ A, const h16* __restrict__ B,
    int K, int m0, int n0, h16* As, h16* Bs, f32x4 (&acc)[4][4]){
  const int tid = threadIdx.x;
  const int lane = tid & 63, quad = lane >> 4, lr = lane & 15;
  const int wid = tid >> 6;
  const int wr = (wid >> 1) * 64, wc = (wid & 1) * 64;
  const int sr = tid >> 2, scc = (tid & 3) * 8;
  const h16* Ag = A + (size_t)(m0 + sr) * K + scc;
  const h16* Bg = B + (size_t)(n0 + sr) * K + scc;
  for (int kt = 0; kt < K; kt += 32){
    gld16(Ag + kt,                 &As[tid * 8]);
    gld16(Ag + (size_t)64*K + kt,  &As[2048 + tid * 8]);
    gld16(Bg + kt,                 &Bs[tid * 8]);
    gld16(Bg + (size_t)64*K + kt,  &Bs[2048 + tid * 8]);
    __syncthreads();
    h16x8 af[4], bfr[4];
#pragma unroll
    for (int r = 0; r < 4; r++) af[r]  = *(const h16x8*)&As[(wr + r*16 + lr) * 32 + quad * 8];
#pragma unroll
    for (int c = 0; c < 4; c++) bfr[c] = *(const h16x8*)&Bs[(wc + c*16 + lr) * 32 + quad * 8];
#pragma unroll
    for (int r = 0; r < 4; r++)
#pragma unroll
      for (int c = 0; c < 4; c++)
        acc[r][c] = __builtin_amdgcn_mfma_f32_16x16x32_f16(af[r], bfr[c], acc[r][c], 0, 0, 0);
    __syncthreads();
  }
}

// ---------- plain GEMM ----------
template<bool OF32>
__global__ __launch_bounds__(256) void k_gemm(const h16* __restrict__ A, const h16* __restrict__ B,
                                              void* __restrict__ Cv, int N, int K){
  __shared__ __attribute__((aligned(16))) h16 As[128*32];
  __shared__ __attribute__((aligned(16))) h16 Bs[128*32];
  const int m0 = blockIdx.y * 128, n0 = blockIdx.x * 128;
  f32x4 acc[4][4] = {};
  gemm_core(A, B, K, m0, n0, As, Bs, acc);
  const int lane = threadIdx.x & 63, quad = lane >> 4, lr = lane & 15;
  const int wid = threadIdx.x >> 6;
  const int wr = (wid >> 1) * 64, wc = (wid & 1) * 64;
#pragma unroll
  for (int r = 0; r < 4; r++)
#pragma unroll
    for (int c = 0; c < 4; c++){
      int row = m0 + wr + r*16 + quad*4;
      int col = n0 + wc + c*16 + lr;
#pragma unroll
      for (int i = 0; i < 4; i++){
        float val = acc[r][c][i];
        if (OF32) ((float*)Cv)[(size_t)(row + i) * N + col] = val;
        else      ((h16*)Cv)[(size_t)(row + i) * N + col] = (h16)val;
      }
    }
}

// ---------- Q GEMM + fused scale/RoPE epilogue -> Qh (stride 200) ----------
__global__ __launch_bounds__(256) void k_gemm_q(const h16* __restrict__ A, const h16* __restrict__ B,
      h16* __restrict__ Qh, const float* __restrict__ cst, const float* __restrict__ snt){
  __shared__ __attribute__((aligned(16))) h16 As[128*32];
  __shared__ __attribute__((aligned(16))) h16 Bs[128*32];
  const int m0 = blockIdx.y * 128, n0 = blockIdx.x * 128;
  f32x4 acc[4][4] = {};
  gemm_core(A, B, QLR, m0, n0, As, Bs, acc);
  const int lane = threadIdx.x & 63, quad = lane >> 4, lr = lane & 15;
  const int wid = threadIdx.x >> 6;
  const int wr = (wid >> 1) * 64, wc = (wid & 1) * 64;
#pragma unroll
  for (int r = 0; r < 4; r++)
#pragma unroll
    for (int c = 0; c < 4; c++){
      int row0 = m0 + wr + r*16 + quad*4;
      int cg = n0 + wc + c*16 + lr;
      int head = cg / 192;
      int inner = cg - head*192;
      h16* outb = Qh + ((size_t)head*S_LEN)*QHS;
      if (inner < 128){
#pragma unroll
        for (int i = 0; i < 4; i++)
          outb[(size_t)(row0+i)*QHS + inner] = (h16)(acc[r][c][i] * SCALE);
      } else {
        int d = (inner - 128) >> 1;
        int isY = inner & 1;
        int ocol = (isY ? 160 : 128) + d;
#pragma unroll
        for (int i = 0; i < 4; i++){
          int rr = row0 + i;
          float cs = cst[rr*32 + d], sn = snt[rr*32 + d];
          float v = acc[r][c][i];
          float w = __shfl_xor(v, 1);
          float out = isY ? (v*cs + w*sn) : (v*cs - w*sn);
          outb[(size_t)rr*QHS + ocol] = (h16)(out * SCALE);
        }
      }
    }
}

// ---------- KV GEMM + fused epilogue: Kh-nope (stride 200) / VT (rotated, via LDS transpose) ----------
__global__ __launch_bounds__(256) void k_gemm_kv(const h16* __restrict__ A, const h16* __restrict__ B,
      h16* __restrict__ Kh, h16* __restrict__ VT){
  __shared__ __attribute__((aligned(16))) h16 As[128*32];
  __shared__ __attribute__((aligned(16))) h16 Bs[128*32];
  __shared__ __attribute__((aligned(16))) h16 tsm[128*132];
  const int m0 = blockIdx.y * 128, n0 = blockIdx.x * 128;
  f32x4 acc[4][4] = {};
  gemm_core(A, B, KVLR, m0, n0, As, Bs, acc);
  const int tid = threadIdx.x;
  const int lane = tid & 63, quad = lane >> 4, lr = lane & 15;
  const int wid = tid >> 6;
  const int wr = (wid >> 1) * 64, wc = (wid & 1) * 64;
  const int head = n0 >> 8;
  if ((n0 & 128) == 0){
#pragma unroll
    for (int r = 0; r < 4; r++)
#pragma unroll
      for (int c = 0; c < 4; c++){
        int row0 = m0 + wr + r*16 + quad*4;
        int inner = wc + c*16 + lr;
#pragma unroll
        for (int i = 0; i < 4; i++)
          Kh[((size_t)head*S_LEN + row0 + i)*QHS + inner] = (h16)acc[r][c][i];
      }
  } else {
#pragma unroll
    for (int r = 0; r < 4; r++)
#pragma unroll
      for (int c = 0; c < 4; c++){
        int lrow = wr + r*16 + quad*4;
        int dv = wc + c*16 + lr;
#pragma unroll
        for (int i = 0; i < 4; i++)
          tsm[(lrow + i)*132 + dv] = (h16)acc[r][c][i];
      }
    __syncthreads();
    int dv = tid >> 1, sh = (tid & 1) * 64;
    h16* vout = VT + ((size_t)(head*VDIM + dv))*S_LEN + m0 + sh;
#pragma unroll
    for (int ko = 0; ko < 8; ko++){
      h16x8 o;
#pragma unroll
      for (int e = 0; e < 8; e++) o[e] = tsm[(sh + ko*8 + e)*132 + dv];
      *(h16x8*)(vout + ((ko*8 + 8*(dv & 7)) & 63)) = o;
    }
  }
}

// ---------- RMSNorm + k_pe RoPE (writes Kh rope cols for all heads) + cos/sin tables ----------
__global__ __launch_bounds__(256) void k_norm(const h16* __restrict__ Cc,
      const float* __restrict__ qw, const float* __restrict__ kw, const int* __restrict__ pos_ids,
      h16* __restrict__ qln, h16* __restrict__ kvln, h16* __restrict__ Kh,
      float* __restrict__ cst, float* __restrict__ snt){
  const int s = blockIdx.x, tid = threadIdx.x;
  __shared__ float red[8];
  __shared__ h16 kpe_s[64];
  const h16* c1 = Cc + (size_t)s * 2176;
  float v[6]; float ss = 0.f;
#pragma unroll
  for (int i = 0; i < 6; i++){ v[i] = (float)c1[tid + i*256]; ss += v[i]*v[i]; }
  for (int off = 32; off > 0; off >>= 1) ss += __shfl_down(ss, off);
  if ((tid & 63) == 0) red[tid >> 6] = ss;
  __syncthreads();
  float rq = rsqrtf((red[0]+red[1]+red[2]+red[3]) / (float)QLR + 1e-6f);
#pragma unroll
  for (int i = 0; i < 6; i++)
    qln[(size_t)s * QLR + tid + i*256] = (h16)(qw[tid + i*256] * v[i] * rq);

  const h16* ck = c1 + QLR;
  float w0 = (float)ck[tid], w1 = (float)ck[tid + 256];
  float ss2 = w0*w0 + w1*w1;
  for (int off = 32; off > 0; off >>= 1) ss2 += __shfl_down(ss2, off);
  if ((tid & 63) == 0) red[4 + (tid >> 6)] = ss2;
  __syncthreads();
  float rk = rsqrtf((red[4]+red[5]+red[6]+red[7]) / (float)KVLR + 1e-6f);
  kvln[(size_t)s * KVLR + tid]       = (h16)(kw[tid] * w0 * rk);
  kvln[(size_t)s * KVLR + tid + 256] = (h16)(kw[tid + 256] * w1 * rk);

  if (tid < 32){
    int d = tid;
    float x = (float)ck[KVLR + 2*d];
    float y = (float)ck[KVLR + 2*d + 1];
    float a = (float)pos_ids[s] * exp2f(FREQC * (float)d);
    float cs = cosf(a), sn = sinf(a);
    cst[s*32 + d] = cs; snt[s*32 + d] = sn;
    kpe_s[d]      = (h16)(x*cs - y*sn);
    kpe_s[32 + d] = (h16)(y*cs + x*sn);
  }
  __syncthreads();
  {
    int h = tid >> 4, seg = (tid & 15) * 4;
    h16x4 o = { kpe_s[seg], kpe_s[seg+1], kpe_s[seg+2], kpe_s[seg+3] };
    *(h16x4*)&Kh[((size_t)h*S_LEN + s)*QHS + 128 + seg] = o;
  }
}

// ---------- causal flash, S^T form: BM=128, BKV=64, split-KV <=8, no P-LDS ----------
__global__ __launch_bounds__(256, 3) void k_flash(const h16* __restrict__ Qh, const h16* __restrict__ Kh,
      const h16* __restrict__ VT, h16* __restrict__ Opart, float* __restrict__ ml){
  const int tile = 15 - blockIdx.x;   // most work first
  const int h = blockIdx.y;
  const int p = blockIdx.z;
  const int jcount = 2*tile + 2;
  const int jlo = p * 8;
  if (jlo >= jcount) return;
  const int jhi = min(jlo + 8, jcount);
  const int m0 = tile * 128;
  __shared__ __attribute__((aligned(16))) h16 Ksm[64*QHS];   // 25600 B
  __shared__ __attribute__((aligned(16))) h16 Vsm[128*64];   // 16384 B
  const int tid = threadIdx.x, wid = tid >> 6, lane = tid & 63, quad = lane >> 4, lr = lane & 15;

  // Q fragments direct from global (once per block); B-operand role
  const h16* Qbase = Qh + ((size_t)h*S_LEN + m0)*QHS;
  h16x8 qf[2][6];
#pragma unroll
  for (int rt = 0; rt < 2; rt++)
#pragma unroll
    for (int ks = 0; ks < 6; ks++)
      qf[rt][ks] = *(const h16x8*)(Qbase + (size_t)(wid*32 + rt*16 + lr)*QHS + ks*32 + quad*8);

  float mst[2] = {-1e30f, -1e30f}, lst[2] = {0.f, 0.f};
  f32x4 oacc[2][8] = {};   // O^T: row=dv (8 tiles), col=q (2 rt)

  const int srcA = (((2*quad)    & 3) << 4) + lr;
  const int srcB = (((2*quad + 1)& 3) << 4) + lr;
  const bool loq = (quad < 2);

  for (int j = jlo; j < jhi; ++j){
    const h16* Kg = Kh + ((size_t)h*S_LEN + j*64)*QHS;
#pragma unroll
    for (int i = 0; i < 6; i++) gld16(Kg + i*2048 + tid*8, &Ksm[i*2048 + tid*8]);
    if (tid < 64) gld16(Kg + 12288 + tid*8, &Ksm[12288 + tid*8]);
    const h16* Vg = VT + (size_t)h * VDIM * S_LEN + (size_t)j * 64;
#pragma unroll
    for (int i = 0; i < 4; i++)
      gld16(Vg + (size_t)(i*32 + (tid >> 3)) * S_LEN + (tid & 7)*8, &Vsm[i*2048 + tid*8]);
    __syncthreads();

    // S^T = K·Q^T : A=K-frag (m=kv), B=Q-frag (n=q)
    f32x4 sc[2][4] = {};
#pragma unroll
    for (int ks = 0; ks < 6; ks++)
#pragma unroll
      for (int ct = 0; ct < 4; ct++){
        h16x8 kf = *(const h16x8*)&Ksm[(ct*16 + lr)*QHS + ks*32 + quad*8];
        sc[0][ct] = __builtin_amdgcn_mfma_f32_16x16x32_f16(kf, qf[0][ks], sc[0][ct], 0,0,0);
        sc[1][ct] = __builtin_amdgcn_mfma_f32_16x16x32_f16(kf, qf[1][ks], sc[1][ct], 0,0,0);
      }

    if (j >= 2*tile){
      // mask: kv = j*64 + ct*16 + quad*4 + i ; q = m0 + wid*32 + rt*16 + lr
#pragma unroll
      for (int rt = 0; rt < 2; rt++){
        int qabs = m0 + wid*32 + rt*16 + lr;
#pragma unroll
        for (int ct = 0; ct < 4; ct++){
          int kv0 = j*64 + ct*16 + quad*4;
#pragma unroll
          for (int i = 0; i < 4; i++)
            if (kv0 + i > qabs) sc[rt][ct][i] = -1e30f;
        }
      }
    }

    long long pk[2][4];   // exp'd P^T packed as h16x4 per (rt,ct)
#pragma unroll
    for (int rt = 0; rt < 2; rt++){
      float m = -1e30f;
#pragma unroll
      for (int ct = 0; ct < 4; ct++)
#pragma unroll
        for (int i = 0; i < 4; i++) m = fmaxf(m, sc[rt][ct][i]);
      m = fmaxf(m, __shfl_xor(m, 16));
      m = fmaxf(m, __shfl_xor(m, 32));
      float mn = fmaxf(fmaxf(mst[rt], m), -1e29f);
      float al = __expf(mst[rt] - mn);
      mst[rt] = mn;
      float rs = 0.f;
#pragma unroll
      for (int ct = 0; ct < 4; ct++){
        h16x4 e4;
#pragma unroll
        for (int i = 0; i < 4; i++){
          float e = __expf(sc[rt][ct][i] - mn);
          rs += e;
          e4[i] = (h16)e;
        }
        __builtin_memcpy(&pk[rt][ct], &e4, 8);
      }
      rs += __shfl_xor(rs, 16);
      rs += __shfl_xor(rs, 32);
      lst[rt] = lst[rt]*al + rs;
#pragma unroll
      for (int oc = 0; oc < 8; oc++)
#pragma unroll
        for (int i = 0; i < 4; i++) oacc[rt][oc][i] *= al;
    }

    // O^T += V^T · P : A=V^T-frag, B=P^T-frag (built by register shuffle)
#pragma unroll
    for (int ks2 = 0; ks2 < 2; ks2++){
      h16x8 pfr[2];
#pragma unroll
      for (int rt = 0; rt < 2; rt++){
        long long la = __shfl(pk[rt][2*ks2],     srcA);
        long long lb = __shfl(pk[rt][2*ks2 + 1], srcA);
        long long ha = __shfl(pk[rt][2*ks2],     srcB);
        long long hb = __shfl(pk[rt][2*ks2 + 1], srcB);
        long long lo = loq ? la : lb;
        long long hi = loq ? ha : hb;
        __builtin_memcpy(&pfr[rt],               &lo, 8);
        __builtin_memcpy(((char*)&pfr[rt]) + 8,  &hi, 8);
      }
      int cv = (ks2*32 + quad*8 + 8*(lr & 7)) & 63;
#pragma unroll
      for (int oc = 0; oc < 8; oc++){
        h16x8 vf = *(const h16x8*)&Vsm[(oc*16 + lr)*64 + cv];
        oacc[0][oc] = __builtin_amdgcn_mfma_f32_16x16x32_f16(vf, pfr[0], oacc[0][oc], 0,0,0);
        oacc[1][oc] = __builtin_amdgcn_mfma_f32_16x16x32_f16(vf, pfr[1], oacc[1][oc], 0,0,0);
      }
    }
    __syncthreads();
  }

  // epilogue: O^T layout -> Op[q][dv] via h16x4 stores (dv = oc*16 + quad*4 + i, q = wid*32+rt*16+lr)
  const int part = (tile*NHEAD + h)*4 + p;
  h16* Op = Opart + (size_t)part * 16384;
#pragma unroll
  for (int rt = 0; rt < 2; rt++){
    int r = wid*32 + rt*16 + lr;
#pragma unroll
    for (int oc = 0; oc < 8; oc++){
      h16x4 o = { (h16)oacc[rt][oc][0], (h16)oacc[rt][oc][1], (h16)oacc[rt][oc][2], (h16)oacc[rt][oc][3] };
      *(h16x4*)&Op[r*128 + oc*16 + quad*4] = o;
    }
    if (quad == 0){
      ml[(size_t)part*256 + r*2]     = mst[rt];
      ml[(size_t)part*256 + r*2 + 1] = lst[rt];
    }
  }
}

// ---------- LSE-combine partials -> Ob ----------
__global__ __launch_bounds__(256) void k_comb(const h16* __restrict__ Opart, const float* __restrict__ ml,
                                              h16* __restrict__ Ob){
  const int t = blockIdx.x, h = blockIdx.y, tid = threadIdx.x;
  const int P = (2*t + 9) >> 3;   // ceil((2t+2)/8)
  const int r = tid >> 1, c0 = (tid & 1) * 64;
  const int base = (t*NHEAD + h)*4;
  float w[4]; float M = -1e30f, denom = 0.f;
  for (int p = 0; p < P; p++) M = fmaxf(M, ml[(size_t)(base+p)*256 + r*2]);
  for (int p = 0; p < P; p++){
    w[p] = __expf(ml[(size_t)(base+p)*256 + r*2] - M);
    denom += w[p] * ml[(size_t)(base+p)*256 + r*2 + 1];
  }
  float inv = 1.f / denom;
#pragma unroll
  for (int ch = 0; ch < 8; ch++){
    float a[8] = {};
    for (int p = 0; p < P; p++){
      h16x8 v = *(const h16x8*)&Opart[(size_t)(base+p)*16384 + r*128 + c0 + ch*8];
#pragma unroll
      for (int e = 0; e < 8; e++) a[e] += w[p] * (float)v[e];
    }
    h16x8 o;
#pragma unroll
    for (int e = 0; e < 8; e++) o[e] = (h16)(a[e] * inv);
    *(h16x8*)&Ob[((size_t)(t*128 + r))*(NHEAD*VDIM) + h*VDIM + c0 + ch*8] = o;
  }
}

extern "C" void kernel_launch(void* const* d_in, const int* in_sizes, int n_in,
                              void* d_out, int out_size, void* d_ws, size_t ws_size,
                              hipStream_t stream){
  const float* hidden = (const float*)d_in[0];
  const int*   pos    = (const int*)  d_in[1];
  const float* Wqa    = (const float*)d_in[2];
  const float* qaw    = (const float*)d_in[3];
  const float* Wqb    = (const float*)d_in[4];
  const float* Wkva   = (const float*)d_in[5];
  const float* kvw    = (const float*)d_in[6];
  const float* Wkvb   = (const float*)d_in[7];
  const float* Wo     = (const float*)d_in[8];

  h16* ws = (h16*)d_ws;
  size_t off = 0;
  auto take = [&](size_t n){ h16* p = ws + off; off += n; return p; };
  h16* hb    = take(2048ull * 2048);
  h16* WoT   = take(2048ull * 2048);
  h16* Wc    = take(2176ull * 2048);   // alias region start (dead before flash)
  h16* WqbT  = take(3072ull * 1536);
  h16* WkvbT = take(4096ull * 512);
  h16* Ccomb = take(2048ull * 2176);
  h16* qln   = take(2048ull * 1536);
  h16* kvln  = take(2048ull * 512);    // alias region end
  float* cst = (float*)take(2048ull * 64);
  float* snt = (float*)take(2048ull * 64);
  h16* Qh    = take(16ull * 2048 * QHS);
  h16* Kh    = take(16ull * 2048 * QHS);
  h16* VT    = take(16ull * 128 * 2048);
  h16* Ob    = hb;                      // hb dead after Ccomb GEMM
  h16*   Opart = Wc;                    // 16*16*4*16384 h16 = 33.6 MB within 39.8 MB region
  float* mlbuf = (float*)(Wc + 16ull*16*4*16384);  // +0.5 MB

  k_cvt<<<4096, 256, 0, stream>>>(hidden, hb, 1048576);
  k_tc<<<dim3(24, 32), 256, 0, stream>>>(Wqa,  Wc,                 2048, 1536);
  k_tc<<<dim3( 9, 32), 256, 0, stream>>>(Wkva, Wc + 1536ull*2048,  2048, 576);
  k_tc<<<dim3(48, 24), 256, 0, stream>>>(Wqb,  WqbT,  1536, 3072);
  k_tc<<<dim3(64,  8), 256, 0, stream>>>(Wkvb, WkvbT, 512,  4096);
  k_tc<<<dim3(32, 32), 256, 0, stream>>>(Wo,   WoT,   2048, 2048);

  k_gemm<false><<<dim3(17, 16), 256, 0, stream>>>(hb, Wc, Ccomb, 2176, 2048);
  k_norm<<<2048, 256, 0, stream>>>(Ccomb, qaw, kvw, pos, qln, kvln, Kh, cst, snt);
  k_gemm_q <<<dim3(24, 16), 256, 0, stream>>>(qln,  WqbT,  Qh, cst, snt);
  k_gemm_kv<<<dim3(32, 16), 256, 0, stream>>>(kvln, WkvbT, Kh, VT);
  k_flash<<<dim3(16, 16, 4), 256, 0, stream>>>(Qh, Kh, VT, Opart, mlbuf);
  k_comb<<<dim3(16, 16), 256, 0, stream>>>(Opart, mlbuf, Ob);
  k_gemm<true><<<dim3(16, 16), 256, 0, stream>>>(Ob, WoT, d_out, 2048, 2048);
}

// Round 9
// 407.129 us; speedup vs baseline: 1.0037x; 1.0037x over previous
//
#include <hip/hip_runtime.h>
#include <hip/hip_bf16.h>

typedef unsigned short u16;
typedef _Float16 h16;
typedef h16 h16x8 __attribute__((ext_vector_type(8)));
typedef h16 h16x4 __attribute__((ext_vector_type(4)));
typedef float f32x4 __attribute__((ext_vector_type(4)));

#define S_LEN 2048
#define QLR   1536
#define KVLR  512
#define NHEAD 16
#define QHD   192
#define QHS   200   // padded row stride for Qh/Kh
#define VDIM  128
#define SCALE 0.07216878364870322f   // 192^-0.5
#define FREQC (-0.4152410118609203f) // -log2(10000)/32

__device__ __forceinline__ void gld16(const h16* g, h16* l){
  __builtin_amdgcn_global_load_lds((__attribute__((address_space(1))) const void*)g,
                                   (__attribute__((address_space(3))) void*)l, 16, 0, 0);
}

// ---------- fp32 -> fp16 elementwise ----------
__global__ __launch_bounds__(256) void k_cvt(const float* __restrict__ in, h16* __restrict__ out, int n4){
  int i = blockIdx.x * 256 + threadIdx.x;
  if (i < n4){
    float4 v = ((const float4*)in)[i];
    h16x4 o = { (h16)v.x, (h16)v.y, (h16)v.z, (h16)v.w };
    ((h16x4*)out)[i] = o;
  }
}

// ---------- fp32 KxN -> fp16 NxK transpose (64x64 tiles) ----------
__global__ __launch_bounds__(256) void k_tc(const float* __restrict__ W, h16* __restrict__ WT, int K, int N){
  __shared__ float t[64][65];
  int k0 = blockIdx.y * 64, n0 = blockIdx.x * 64;
  int tid = threadIdx.x;
  int r = tid >> 4, c4 = (tid & 15) * 4;
#pragma unroll
  for (int it = 0; it < 4; it++){
    float4 v = *(const float4*)(W + (size_t)(k0 + it*16 + r) * N + n0 + c4);
    t[it*16+r][c4] = v.x; t[it*16+r][c4+1] = v.y; t[it*16+r][c4+2] = v.z; t[it*16+r][c4+3] = v.w;
  }
  __syncthreads();
  int n = tid >> 2, k16 = (tid & 3) * 16;
  h16x8 o0, o1;
#pragma unroll
  for (int e = 0; e < 8; e++){ o0[e] = (h16)t[k16 + e][n]; o1[e] = (h16)t[k16 + 8 + e][n]; }
  h16* dst = WT + (size_t)(n0 + n) * K + k0 + k16;
  *(h16x8*)dst = o0;
  *(h16x8*)(dst + 8) = o1;
}

// ---------- shared GEMM mainloop ----------
__device__ __forceinline__ void gemm_core(const h16* __restrict__ A, const h16* __restrict__ B,
    int K, int m0, int n0, h16* As, h16* Bs, f32x4 (&acc)[4][4]){
  const int tid = threadIdx.x;
  const int lane = tid & 63, quad = lane >> 4, lr = lane & 15;
  const int wid = tid >> 6;
  const int wr = (wid >> 1) * 64, wc = (wid & 1) * 64;
  const int sr = tid >> 2, scc = (tid & 3) * 8;
  const h16* Ag = A + (size_t)(m0 + sr) * K + scc;
  const h16* Bg = B + (size_t)(n0 + sr) * K + scc;
  for (int kt = 0; kt < K; kt += 32){
    gld16(Ag + kt,                 &As[tid * 8]);
    gld16(Ag + (size_t)64*K + kt,  &As[2048 + tid * 8]);
    gld16(Bg + kt,                 &Bs[tid * 8]);
    gld16(Bg + (size_t)64*K + kt,  &Bs[2048 + tid * 8]);
    __syncthreads();
    h16x8 af[4], bfr[4];
#pragma unroll
    for (int r = 0; r < 4; r++) af[r]  = *(const h16x8*)&As[(wr + r*16 + lr) * 32 + quad * 8];
#pragma unroll
    for (int c = 0; c < 4; c++) bfr[c] = *(const h16x8*)&Bs[(wc + c*16 + lr) * 32 + quad * 8];
#pragma unroll
    for (int r = 0; r < 4; r++)
#pragma unroll
      for (int c = 0; c < 4; c++)
        acc[r][c] = __builtin_amdgcn_mfma_f32_16x16x32_f16(af[r], bfr[c], acc[r][c], 0, 0, 0);
    __syncthreads();
  }
}

// ---------- plain GEMM ----------
template<bool OF32>
__global__ __launch_bounds__(256) void k_gemm(const h16* __restrict__ A, const h16* __restrict__ B,
                                              void* __restrict__ Cv, int N, int K){
  __shared__ __attribute__((aligned(16))) h16 As[128*32];
  __shared__ __attribute__((aligned(16))) h16 Bs[128*32];
  const int m0 = blockIdx.y * 128, n0 = blockIdx.x * 128;
  f32x4 acc[4][4] = {};
  gemm_core(A, B, K, m0, n0, As, Bs, acc);
  const int lane = threadIdx.x & 63, quad = lane >> 4, lr = lane & 15;
  const int wid = threadIdx.x >> 6;
  const int wr = (wid >> 1) * 64, wc = (wid & 1) * 64;
#pragma unroll
  for (int r = 0; r < 4; r++)
#pragma unroll
    for (int c = 0; c < 4; c++){
      int row = m0 + wr + r*16 + quad*4;
      int col = n0 + wc + c*16 + lr;
#pragma unroll
      for (int i = 0; i < 4; i++){
        float val = acc[r][c][i];
        if (OF32) ((float*)Cv)[(size_t)(row + i) * N + col] = val;
        else      ((h16*)Cv)[(size_t)(row + i) * N + col] = (h16)val;
      }
    }
}

// ---------- Q GEMM + fused scale/RoPE epilogue -> Qh (stride 200) ----------
__global__ __launch_bounds__(256) void k_gemm_q(const h16* __restrict__ A, const h16* __restrict__ B,
      h16* __restrict__ Qh, const float* __restrict__ cst, const float* __restrict__ snt){
  __shared__ __attribute__((aligned(16))) h16 As[128*32];
  __shared__ __attribute__((aligned(16))) h16 Bs[128*32];
  const int m0 = blockIdx.y * 128, n0 = blockIdx.x * 128;
  f32x4 acc[4][4] = {};
  gemm_core(A, B, QLR, m0, n0, As, Bs, acc);
  const int lane = threadIdx.x & 63, quad = lane >> 4, lr = lane & 15;
  const int wid = threadIdx.x >> 6;
  const int wr = (wid >> 1) * 64, wc = (wid & 1) * 64;
#pragma unroll
  for (int r = 0; r < 4; r++)
#pragma unroll
    for (int c = 0; c < 4; c++){
      int row0 = m0 + wr + r*16 + quad*4;
      int cg = n0 + wc + c*16 + lr;
      int head = cg / 192;
      int inner = cg - head*192;
      h16* outb = Qh + ((size_t)head*S_LEN)*QHS;
      if (inner < 128){
#pragma unroll
        for (int i = 0; i < 4; i++)
          outb[(size_t)(row0+i)*QHS + inner] = (h16)(acc[r][c][i] * SCALE);
      } else {
        int d = (inner - 128) >> 1;
        int isY = inner & 1;
        int ocol = (isY ? 160 : 128) + d;
#pragma unroll
        for (int i = 0; i < 4; i++){
          int rr = row0 + i;
          float cs = cst[rr*32 + d], sn = snt[rr*32 + d];
          float v = acc[r][c][i];
          float w = __shfl_xor(v, 1);
          float out = isY ? (v*cs + w*sn) : (v*cs - w*sn);
          outb[(size_t)rr*QHS + ocol] = (h16)(out * SCALE);
        }
      }
    }
}

// ---------- KV GEMM + fused epilogue: Kh-nope (stride 200) / VT (rotated, via LDS transpose) ----------
__global__ __launch_bounds__(256) void k_gemm_kv(const h16* __restrict__ A, const h16* __restrict__ B,
      h16* __restrict__ Kh, h16* __restrict__ VT){
  __shared__ __attribute__((aligned(16))) h16 As[128*32];
  __shared__ __attribute__((aligned(16))) h16 Bs[128*32];
  __shared__ __attribute__((aligned(16))) h16 tsm[128*132];
  const int m0 = blockIdx.y * 128, n0 = blockIdx.x * 128;
  f32x4 acc[4][4] = {};
  gemm_core(A, B, KVLR, m0, n0, As, Bs, acc);
  const int tid = threadIdx.x;
  const int lane = tid & 63, quad = lane >> 4, lr = lane & 15;
  const int wid = tid >> 6;
  const int wr = (wid >> 1) * 64, wc = (wid & 1) * 64;
  const int head = n0 >> 8;
  if ((n0 & 128) == 0){
#pragma unroll
    for (int r = 0; r < 4; r++)
#pragma unroll
      for (int c = 0; c < 4; c++){
        int row0 = m0 + wr + r*16 + quad*4;
        int inner = wc + c*16 + lr;
#pragma unroll
        for (int i = 0; i < 4; i++)
          Kh[((size_t)head*S_LEN + row0 + i)*QHS + inner] = (h16)acc[r][c][i];
      }
  } else {
#pragma unroll
    for (int r = 0; r < 4; r++)
#pragma unroll
      for (int c = 0; c < 4; c++){
        int lrow = wr + r*16 + quad*4;
        int dv = wc + c*16 + lr;
#pragma unroll
        for (int i = 0; i < 4; i++)
          tsm[(lrow + i)*132 + dv] = (h16)acc[r][c][i];
      }
    __syncthreads();
    int dv = tid >> 1, sh = (tid & 1) * 64;
    h16* vout = VT + ((size_t)(head*VDIM + dv))*S_LEN + m0 + sh;
#pragma unroll
    for (int ko = 0; ko < 8; ko++){
      h16x8 o;
#pragma unroll
      for (int e = 0; e < 8; e++) o[e] = tsm[(sh + ko*8 + e)*132 + dv];
      *(h16x8*)(vout + ((ko*8 + 8*(dv & 7)) & 63)) = o;
    }
  }
}

// ---------- RMSNorm + k_pe RoPE (writes Kh rope cols for all heads) + cos/sin tables ----------
__global__ __launch_bounds__(256) void k_norm(const h16* __restrict__ Cc,
      const float* __restrict__ qw, const float* __restrict__ kw, const int* __restrict__ pos_ids,
      h16* __restrict__ qln, h16* __restrict__ kvln, h16* __restrict__ Kh,
      float* __restrict__ cst, float* __restrict__ snt){
  const int s = blockIdx.x, tid = threadIdx.x;
  __shared__ float red[8];
  __shared__ h16 kpe_s[64];
  const h16* c1 = Cc + (size_t)s * 2176;
  float v[6]; float ss = 0.f;
#pragma unroll
  for (int i = 0; i < 6; i++){ v[i] = (float)c1[tid + i*256]; ss += v[i]*v[i]; }
  for (int off = 32; off > 0; off >>= 1) ss += __shfl_down(ss, off);
  if ((tid & 63) == 0) red[tid >> 6] = ss;
  __syncthreads();
  float rq = rsqrtf((red[0]+red[1]+red[2]+red[3]) / (float)QLR + 1e-6f);
#pragma unroll
  for (int i = 0; i < 6; i++)
    qln[(size_t)s * QLR + tid + i*256] = (h16)(qw[tid + i*256] * v[i] * rq);

  const h16* ck = c1 + QLR;
  float w0 = (float)ck[tid], w1 = (float)ck[tid + 256];
  float ss2 = w0*w0 + w1*w1;
  for (int off = 32; off > 0; off >>= 1) ss2 += __shfl_down(ss2, off);
  if ((tid & 63) == 0) red[4 + (tid >> 6)] = ss2;
  __syncthreads();
  float rk = rsqrtf((red[4]+red[5]+red[6]+red[7]) / (float)KVLR + 1e-6f);
  kvln[(size_t)s * KVLR + tid]       = (h16)(kw[tid] * w0 * rk);
  kvln[(size_t)s * KVLR + tid + 256] = (h16)(kw[tid + 256] * w1 * rk);

  if (tid < 32){
    int d = tid;
    float x = (float)ck[KVLR + 2*d];
    float y = (float)ck[KVLR + 2*d + 1];
    float a = (float)pos_ids[s] * exp2f(FREQC * (float)d);
    float cs = cosf(a), sn = sinf(a);
    cst[s*32 + d] = cs; snt[s*32 + d] = sn;
    kpe_s[d]      = (h16)(x*cs - y*sn);
    kpe_s[32 + d] = (h16)(y*cs + x*sn);
  }
  __syncthreads();
  {
    int h = tid >> 4, seg = (tid & 15) * 4;
    h16x4 o = { kpe_s[seg], kpe_s[seg+1], kpe_s[seg+2], kpe_s[seg+3] };
    *(h16x4*)&Kh[((size_t)h*S_LEN + s)*QHS + 128 + seg] = o;
  }
}

// ---------- causal flash, S^T form: BM=128, BKV=64, split-KV <=8, per-wave chunked Psm ----------
__global__ __launch_bounds__(256, 3) void k_flash(const h16* __restrict__ Qh, const h16* __restrict__ Kh,
      const h16* __restrict__ VT, h16* __restrict__ Opart, float* __restrict__ ml){
  const int tile = 15 - blockIdx.x;   // most work first
  const int h = blockIdx.y;
  const int p = blockIdx.z;
  const int jcount = 2*tile + 2;
  const int jlo = p * 8;
  if (jlo >= jcount) return;
  const int jhi = min(jlo + 8, jcount);
  const int m0 = tile * 128;
  __shared__ __attribute__((aligned(16))) h16 Ksm[64*QHS];   // 25600 B
  __shared__ __attribute__((aligned(16))) h16 Vsm[128*64];   // 16384 B
  __shared__ __attribute__((aligned(16))) h16 Psm[4*32*36];  // 9216 B, per-wave [32 q][36 kv-chunk]
  const int tid = threadIdx.x, wid = tid >> 6, lane = tid & 63, quad = lane >> 4, lr = lane & 15;
  h16* Pw = Psm + wid*(32*36);

  // Q fragments direct from global (once per block); B-operand role
  const h16* Qbase = Qh + ((size_t)h*S_LEN + m0)*QHS;
  h16x8 qf[2][6];
#pragma unroll
  for (int rt = 0; rt < 2; rt++)
#pragma unroll
    for (int ks = 0; ks < 6; ks++)
      qf[rt][ks] = *(const h16x8*)(Qbase + (size_t)(wid*32 + rt*16 + lr)*QHS + ks*32 + quad*8);

  float mst[2] = {-1e30f, -1e30f}, lst[2] = {0.f, 0.f};
  f32x4 oacc[2][8] = {};   // O^T: row=dv (8 tiles), col=q (2 rt)

  for (int j = jlo; j < jhi; ++j){
    const h16* Kg = Kh + ((size_t)h*S_LEN + j*64)*QHS;
#pragma unroll
    for (int i = 0; i < 6; i++) gld16(Kg + i*2048 + tid*8, &Ksm[i*2048 + tid*8]);
    if (tid < 64) gld16(Kg + 12288 + tid*8, &Ksm[12288 + tid*8]);
    const h16* Vg = VT + (size_t)h * VDIM * S_LEN + (size_t)j * 64;
#pragma unroll
    for (int i = 0; i < 4; i++)
      gld16(Vg + (size_t)(i*32 + (tid >> 3)) * S_LEN + (tid & 7)*8, &Vsm[i*2048 + tid*8]);
    __syncthreads();

    // S^T = K·Q^T : A=K-frag (m=kv), B=Q-frag (n=q)
    f32x4 sc[2][4] = {};
#pragma unroll
    for (int ks = 0; ks < 6; ks++)
#pragma unroll
      for (int ct = 0; ct < 4; ct++){
        h16x8 kf = *(const h16x8*)&Ksm[(ct*16 + lr)*QHS + ks*32 + quad*8];
        sc[0][ct] = __builtin_amdgcn_mfma_f32_16x16x32_f16(kf, qf[0][ks], sc[0][ct], 0,0,0);
        sc[1][ct] = __builtin_amdgcn_mfma_f32_16x16x32_f16(kf, qf[1][ks], sc[1][ct], 0,0,0);
      }

    if (j >= 2*tile){
      // mask: kv = j*64 + ct*16 + quad*4 + i ; q = m0 + wid*32 + rt*16 + lr
#pragma unroll
      for (int rt = 0; rt < 2; rt++){
        int qabs = m0 + wid*32 + rt*16 + lr;
#pragma unroll
        for (int ct = 0; ct < 4; ct++){
          int kv0 = j*64 + ct*16 + quad*4;
#pragma unroll
          for (int i = 0; i < 4; i++)
            if (kv0 + i > qabs) sc[rt][ct][i] = -1e30f;
        }
      }
    }

    h16x4 e4[2][4];
#pragma unroll
    for (int rt = 0; rt < 2; rt++){
      float m = -1e30f;
#pragma unroll
      for (int ct = 0; ct < 4; ct++)
#pragma unroll
        for (int i = 0; i < 4; i++) m = fmaxf(m, sc[rt][ct][i]);
      m = fmaxf(m, __shfl_xor(m, 16));
      m = fmaxf(m, __shfl_xor(m, 32));
      float mn = fmaxf(fmaxf(mst[rt], m), -1e29f);
      float al = __expf(mst[rt] - mn);
      mst[rt] = mn;
      float rs = 0.f;
#pragma unroll
      for (int ct = 0; ct < 4; ct++)
#pragma unroll
        for (int i = 0; i < 4; i++){
          float e = __expf(sc[rt][ct][i] - mn);
          rs += e;
          e4[rt][ct][i] = (h16)e;
        }
      rs += __shfl_xor(rs, 16);
      rs += __shfl_xor(rs, 32);
      lst[rt] = lst[rt]*al + rs;
#pragma unroll
      for (int oc = 0; oc < 8; oc++)
#pragma unroll
        for (int i = 0; i < 4; i++) oacc[rt][oc][i] *= al;
    }

    // PV in two 32-kv chunks through per-wave Psm (in-order DS pipe: no barrier needed)
#pragma unroll
    for (int c2 = 0; c2 < 2; c2++){
#pragma unroll
      for (int rt = 0; rt < 2; rt++){
        *(h16x4*)&Pw[(rt*16 + lr)*36 + quad*4]      = e4[rt][2*c2];
        *(h16x4*)&Pw[(rt*16 + lr)*36 + 16 + quad*4] = e4[rt][2*c2 + 1];
      }
      h16x8 pfr[2];
#pragma unroll
      for (int rt = 0; rt < 2; rt++)
        pfr[rt] = *(const h16x8*)&Pw[(rt*16 + lr)*36 + quad*8];
      int cv = (c2*32 + quad*8 + 8*(lr & 7)) & 63;
#pragma unroll
      for (int oc = 0; oc < 8; oc++){
        h16x8 vf = *(const h16x8*)&Vsm[(oc*16 + lr)*64 + cv];
        oacc[0][oc] = __builtin_amdgcn_mfma_f32_16x16x32_f16(vf, pfr[0], oacc[0][oc], 0,0,0);
        oacc[1][oc] = __builtin_amdgcn_mfma_f32_16x16x32_f16(vf, pfr[1], oacc[1][oc], 0,0,0);
      }
    }
    __syncthreads();
  }

  // epilogue: O^T -> Op[q][dv] via h16x4 stores
  const int part = (tile*NHEAD + h)*4 + p;
  h16* Op = Opart + (size_t)part * 16384;
#pragma unroll
  for (int rt = 0; rt < 2; rt++){
    int r = wid*32 + rt*16 + lr;
#pragma unroll
    for (int oc = 0; oc < 8; oc++){
      h16x4 o = { (h16)oacc[rt][oc][0], (h16)oacc[rt][oc][1], (h16)oacc[rt][oc][2], (h16)oacc[rt][oc][3] };
      *(h16x4*)&Op[r*128 + oc*16 + quad*4] = o;
    }
    if (quad == 0){
      ml[(size_t)part*256 + r*2]     = mst[rt];
      ml[(size_t)part*256 + r*2 + 1] = lst[rt];
    }
  }
}

// ---------- LSE-combine partials -> Ob ----------
__global__ __launch_bounds__(256) void k_comb(const h16* __restrict__ Opart, const float* __restrict__ ml,
                                              h16* __restrict__ Ob){
  const int t = blockIdx.x, h = blockIdx.y, tid = threadIdx.x;
  const int P = (2*t + 9) >> 3;   // ceil((2t+2)/8)
  const int r = tid >> 1, c0 = (tid & 1) * 64;
  const int base = (t*NHEAD + h)*4;
  float w[4]; float M = -1e30f, denom = 0.f;
  for (int p = 0; p < P; p++) M = fmaxf(M, ml[(size_t)(base+p)*256 + r*2]);
  for (int p = 0; p < P; p++){
    w[p] = __expf(ml[(size_t)(base+p)*256 + r*2] - M);
    denom += w[p] * ml[(size_t)(base+p)*256 + r*2 + 1];
  }
  float inv = 1.f / denom;
#pragma unroll
  for (int ch = 0; ch < 8; ch++){
    float a[8] = {};
    for (int p = 0; p < P; p++){
      h16x8 v = *(const h16x8*)&Opart[(size_t)(base+p)*16384 + r*128 + c0 + ch*8];
#pragma unroll
      for (int e = 0; e < 8; e++) a[e] += w[p] * (float)v[e];
    }
    h16x8 o;
#pragma unroll
    for (int e = 0; e < 8; e++) o[e] = (h16)(a[e] * inv);
    *(h16x8*)&Ob[((size_t)(t*128 + r))*(NHEAD*VDIM) + h*VDIM + c0 + ch*8] = o;
  }
}

extern "C" void kernel_launch(void* const* d_in, const int* in_sizes, int n_in,
                              void* d_out, int out_size, void* d_ws, size_t ws_size,
                              hipStream_t stream){
  const float* hidden = (const float*)d_in[0];
  const int*   pos    = (const int*)  d_in[1];
  const float* Wqa    = (const float*)d_in[2];
  const float* qaw    = (const float*)d_in[3];
  const float* Wqb    = (const float*)d_in[4];
  const float* Wkva   = (const float*)d_in[5];
  const float* kvw    = (const float*)d_in[6];
  const float* Wkvb   = (const float*)d_in[7];
  const float* Wo     = (const float*)d_in[8];

  h16* ws = (h16*)d_ws;
  size_t off = 0;
  auto take = [&](size_t n){ h16* p = ws + off; off += n; return p; };
  h16* hb    = take(2048ull * 2048);
  h16* WoT   = take(2048ull * 2048);
  h16* Wc    = take(2176ull * 2048);   // alias region start (dead before flash)
  h16* WqbT  = take(3072ull * 1536);
  h16* WkvbT = take(4096ull * 512);
  h16* Ccomb = take(2048ull * 2176);
  h16* qln   = take(2048ull * 1536);
  h16* kvln  = take(2048ull * 512);    // alias region end
  float* cst = (float*)take(2048ull * 64);
  float* snt = (float*)take(2048ull * 64);
  h16* Qh    = take(16ull * 2048 * QHS);
  h16* Kh    = take(16ull * 2048 * QHS);
  h16* VT    = take(16ull * 128 * 2048);
  h16* Ob    = hb;                      // hb dead after Ccomb GEMM
  h16*   Opart = Wc;                    // 16*16*4*16384 h16 = 33.6 MB within 39.8 MB region
  float* mlbuf = (float*)(Wc + 16ull*16*4*16384);  // +0.5 MB

  k_cvt<<<4096, 256, 0, stream>>>(hidden, hb, 1048576);
  k_tc<<<dim3(24, 32), 256, 0, stream>>>(Wqa,  Wc,                 2048, 1536);
  k_tc<<<dim3( 9, 32), 256, 0, stream>>>(Wkva, Wc + 1536ull*2048,  2048, 576);
  k_tc<<<dim3(48, 24), 256, 0, stream>>>(Wqb,  WqbT,  1536, 3072);
  k_tc<<<dim3(64,  8), 256, 0, stream>>>(Wkvb, WkvbT, 512,  4096);
  k_tc<<<dim3(32, 32), 256, 0, stream>>>(Wo,   WoT,   2048, 2048);

  k_gemm<false><<<dim3(17, 16), 256, 0, stream>>>(hb, Wc, Ccomb, 2176, 2048);
  k_norm<<<2048, 256, 0, stream>>>(Ccomb, qaw, kvw, pos, qln, kvln, Kh, cst, snt);
  k_gemm_q <<<dim3(24, 16), 256, 0, stream>>>(qln,  WqbT,  Qh, cst, snt);
  k_gemm_kv<<<dim3(32, 16), 256, 0, stream>>>(kvln, WkvbT, Kh, VT);
  k_flash<<<dim3(16, 16, 4), 256, 0, stream>>>(Qh, Kh, VT, Opart, mlbuf);
  k_comb<<<dim3(16, 16), 256, 0, stream>>>(Opart, mlbuf, Ob);
  k_gemm<true><<<dim3(16, 16), 256, 0, stream>>>(Ob, WoT, d_out, 2048, 2048);
}

// Round 10
// 376.674 us; speedup vs baseline: 1.0849x; 1.0809x over previous
//
#include <hip/hip_runtime.h>
#include <hip/hip_bf16.h>

typedef unsigned short u16;
typedef _Float16 h16;
typedef h16 h16x8 __attribute__((ext_vector_type(8)));
typedef h16 h16x4 __attribute__((ext_vector_type(4)));
typedef float f32x4 __attribute__((ext_vector_type(4)));

#define S_LEN 2048
#define QLR   1536
#define KVLR  512
#define NHEAD 16
#define QHD   192
#define QHS   200   // padded row stride for Qh/Kh
#define VDIM  128
#define SCALE 0.07216878364870322f   // 192^-0.5
#define FREQC (-0.4152410118609203f) // -log2(10000)/32

__device__ __forceinline__ void gld16(const h16* g, h16* l){
  __builtin_amdgcn_global_load_lds((__attribute__((address_space(1))) const void*)g,
                                   (__attribute__((address_space(3))) void*)l, 16, 0, 0);
}

// ---------- merged preprocessing: fp32->fp16 cvt + 5 weight transposes ----------
__global__ __launch_bounds__(256) void k_prep(const float* __restrict__ hidden, h16* __restrict__ hb,
      const float* __restrict__ Wqa, const float* __restrict__ Wkva, const float* __restrict__ Wqb,
      const float* __restrict__ Wkvb, const float* __restrict__ Wo,
      h16* __restrict__ Wc, h16* __restrict__ WqbT, h16* __restrict__ WkvbT, h16* __restrict__ WoT){
  int bx = blockIdx.x;
  const int tid = threadIdx.x;
  if (bx < 4096){            // cvt: 4096*256*4 = 4M elements
    int i = bx*256 + tid;
    float4 v = ((const float4*)hidden)[i];
    h16x4 o = { (h16)v.x, (h16)v.y, (h16)v.z, (h16)v.w };
    ((h16x4*)hb)[i] = o;
    return;
  }
  bx -= 4096;
  const float* W; h16* WT; int K, N, nx;
  if (bx < 768)       { W = Wqa;  WT = Wc;                K = 2048; N = 1536; nx = 24; }
  else if (bx < 1056) { bx -= 768;  W = Wkva; WT = Wc + 1536ull*2048; K = 2048; N = 576;  nx = 9;  }
  else if (bx < 2208) { bx -= 1056; W = Wqb;  WT = WqbT;  K = 1536; N = 3072; nx = 48; }
  else if (bx < 2720) { bx -= 2208; W = Wkvb; WT = WkvbT; K = 512;  N = 4096; nx = 64; }
  else                { bx -= 2720; W = Wo;   WT = WoT;   K = 2048; N = 2048; nx = 32; }
  int ty = bx / nx, tx = bx - ty*nx;
  int k0 = ty * 64, n0 = tx * 64;
  __shared__ float t[64][65];
  int r = tid >> 4, c4 = (tid & 15) * 4;
#pragma unroll
  for (int it = 0; it < 4; it++){
    float4 v = *(const float4*)(W + (size_t)(k0 + it*16 + r) * N + n0 + c4);
    t[it*16+r][c4] = v.x; t[it*16+r][c4+1] = v.y; t[it*16+r][c4+2] = v.z; t[it*16+r][c4+3] = v.w;
  }
  __syncthreads();
  int n = tid >> 2, k16 = (tid & 3) * 16;
  h16x8 o0, o1;
#pragma unroll
  for (int e = 0; e < 8; e++){ o0[e] = (h16)t[k16 + e][n]; o1[e] = (h16)t[k16 + 8 + e][n]; }
  h16* dst = WT + (size_t)(n0 + n) * K + k0 + k16;
  *(h16x8*)dst = o0;
  *(h16x8*)(dst + 8) = o1;
}

// ---------- shared GEMM mainloop ----------
__device__ __forceinline__ void gemm_core(const h16* __restrict__ A, const h16* __restrict__ B,
    int K, int m0, int n0, h16* As, h16* Bs, f32x4 (&acc)[4][4]){
  const int tid = threadIdx.x;
  const int lane = tid & 63, quad = lane >> 4, lr = lane & 15;
  const int wid = tid >> 6;
  const int wr = (wid >> 1) * 64, wc = (wid & 1) * 64;
  const int sr = tid >> 2, scc = (tid & 3) * 8;
  const h16* Ag = A + (size_t)(m0 + sr) * K + scc;
  const h16* Bg = B + (size_t)(n0 + sr) * K + scc;
  for (int kt = 0; kt < K; kt += 32){
    gld16(Ag + kt,                 &As[tid * 8]);
    gld16(Ag + (size_t)64*K + kt,  &As[2048 + tid * 8]);
    gld16(Bg + kt,                 &Bs[tid * 8]);
    gld16(Bg + (size_t)64*K + kt,  &Bs[2048 + tid * 8]);
    __syncthreads();
    h16x8 af[4], bfr[4];
#pragma unroll
    for (int r = 0; r < 4; r++) af[r]  = *(const h16x8*)&As[(wr + r*16 + lr) * 32 + quad * 8];
#pragma unroll
    for (int c = 0; c < 4; c++) bfr[c] = *(const h16x8*)&Bs[(wc + c*16 + lr) * 32 + quad * 8];
#pragma unroll
    for (int r = 0; r < 4; r++)
#pragma unroll
      for (int c = 0; c < 4; c++)
        acc[r][c] = __builtin_amdgcn_mfma_f32_16x16x32_f16(af[r], bfr[c], acc[r][c], 0, 0, 0);
    __syncthreads();
  }
}

// ---------- plain GEMM ----------
template<bool OF32>
__global__ __launch_bounds__(256) void k_gemm(const h16* __restrict__ A, const h16* __restrict__ B,
                                              void* __restrict__ Cv, int N, int K){
  __shared__ __attribute__((aligned(16))) h16 As[128*32];
  __shared__ __attribute__((aligned(16))) h16 Bs[128*32];
  const int m0 = blockIdx.y * 128, n0 = blockIdx.x * 128;
  f32x4 acc[4][4] = {};
  gemm_core(A, B, K, m0, n0, As, Bs, acc);
  const int lane = threadIdx.x & 63, quad = lane >> 4, lr = lane & 15;
  const int wid = threadIdx.x >> 6;
  const int wr = (wid >> 1) * 64, wc = (wid & 1) * 64;
#pragma unroll
  for (int r = 0; r < 4; r++)
#pragma unroll
    for (int c = 0; c < 4; c++){
      int row = m0 + wr + r*16 + quad*4;
      int col = n0 + wc + c*16 + lr;
#pragma unroll
      for (int i = 0; i < 4; i++){
        float val = acc[r][c][i];
        if (OF32) ((float*)Cv)[(size_t)(row + i) * N + col] = val;
        else      ((h16*)Cv)[(size_t)(row + i) * N + col] = (h16)val;
      }
    }
}

// ---------- merged Q + KV GEMM (independent -> one launch for occupancy) ----------
__global__ __launch_bounds__(256) void k_gemm_qkv(const h16* __restrict__ qln, const h16* __restrict__ WqbT,
      const h16* __restrict__ kvln, const h16* __restrict__ WkvbT,
      h16* __restrict__ Qh, h16* __restrict__ Kh, h16* __restrict__ VT,
      const float* __restrict__ cst, const float* __restrict__ snt){
  __shared__ __attribute__((aligned(16))) h16 As[128*32];
  __shared__ __attribute__((aligned(16))) h16 Bs[128*32];
  __shared__ __attribute__((aligned(16))) h16 tsm[128*132];
  const int m0 = blockIdx.y * 128;
  const int tid = threadIdx.x;
  const int lane = tid & 63, quad = lane >> 4, lr = lane & 15;
  const int wid = tid >> 6;
  const int wr = (wid >> 1) * 64, wc = (wid & 1) * 64;
  f32x4 acc[4][4] = {};
  if (blockIdx.x < 24){
    // ---- Q path: qln x WqbT with scale/RoPE epilogue -> Qh (stride 200) ----
    const int n0 = blockIdx.x * 128;
    gemm_core(qln, WqbT, QLR, m0, n0, As, Bs, acc);
#pragma unroll
    for (int r = 0; r < 4; r++)
#pragma unroll
      for (int c = 0; c < 4; c++){
        int row0 = m0 + wr + r*16 + quad*4;
        int cg = n0 + wc + c*16 + lr;
        int head = cg / 192;
        int inner = cg - head*192;
        h16* outb = Qh + ((size_t)head*S_LEN)*QHS;
        if (inner < 128){
#pragma unroll
          for (int i = 0; i < 4; i++)
            outb[(size_t)(row0+i)*QHS + inner] = (h16)(acc[r][c][i] * SCALE);
        } else {
          int d = (inner - 128) >> 1;
          int isY = inner & 1;
          int ocol = (isY ? 160 : 128) + d;
#pragma unroll
          for (int i = 0; i < 4; i++){
            int rr = row0 + i;
            float cs = cst[rr*32 + d], sn = snt[rr*32 + d];
            float v = acc[r][c][i];
            float w = __shfl_xor(v, 1);
            float out = isY ? (v*cs + w*sn) : (v*cs - w*sn);
            outb[(size_t)rr*QHS + ocol] = (h16)(out * SCALE);
          }
        }
      }
  } else {
    // ---- KV path: kvln x WkvbT -> Kh nope (stride 200) / VT (rotated via LDS transpose) ----
    const int n0 = (blockIdx.x - 24) * 128;
    gemm_core(kvln, WkvbT, KVLR, m0, n0, As, Bs, acc);
    const int head = n0 >> 8;
    if ((n0 & 128) == 0){
#pragma unroll
      for (int r = 0; r < 4; r++)
#pragma unroll
        for (int c = 0; c < 4; c++){
          int row0 = m0 + wr + r*16 + quad*4;
          int inner = wc + c*16 + lr;
#pragma unroll
          for (int i = 0; i < 4; i++)
            Kh[((size_t)head*S_LEN + row0 + i)*QHS + inner] = (h16)acc[r][c][i];
        }
    } else {
#pragma unroll
      for (int r = 0; r < 4; r++)
#pragma unroll
        for (int c = 0; c < 4; c++){
          int lrow = wr + r*16 + quad*4;
          int dv = wc + c*16 + lr;
#pragma unroll
          for (int i = 0; i < 4; i++)
            tsm[(lrow + i)*132 + dv] = (h16)acc[r][c][i];
        }
      __syncthreads();
      int dv = tid >> 1, sh = (tid & 1) * 64;
      h16* vout = VT + ((size_t)(head*VDIM + dv))*S_LEN + m0 + sh;
#pragma unroll
      for (int ko = 0; ko < 8; ko++){
        h16x8 o;
#pragma unroll
        for (int e = 0; e < 8; e++) o[e] = tsm[(sh + ko*8 + e)*132 + dv];
        *(h16x8*)(vout + ((ko*8 + 8*(dv & 7)) & 63)) = o;
      }
    }
  }
}

// ---------- RMSNorm + k_pe RoPE (writes Kh rope cols for all heads) + cos/sin tables ----------
__global__ __launch_bounds__(256) void k_norm(const h16* __restrict__ Cc,
      const float* __restrict__ qw, const float* __restrict__ kw, const int* __restrict__ pos_ids,
      h16* __restrict__ qln, h16* __restrict__ kvln, h16* __restrict__ Kh,
      float* __restrict__ cst, float* __restrict__ snt){
  const int s = blockIdx.x, tid = threadIdx.x;
  __shared__ float red[8];
  __shared__ h16 kpe_s[64];
  const h16* c1 = Cc + (size_t)s * 2176;
  float v[6]; float ss = 0.f;
#pragma unroll
  for (int i = 0; i < 6; i++){ v[i] = (float)c1[tid + i*256]; ss += v[i]*v[i]; }
  for (int off = 32; off > 0; off >>= 1) ss += __shfl_down(ss, off);
  if ((tid & 63) == 0) red[tid >> 6] = ss;
  __syncthreads();
  float rq = rsqrtf((red[0]+red[1]+red[2]+red[3]) / (float)QLR + 1e-6f);
#pragma unroll
  for (int i = 0; i < 6; i++)
    qln[(size_t)s * QLR + tid + i*256] = (h16)(qw[tid + i*256] * v[i] * rq);

  const h16* ck = c1 + QLR;
  float w0 = (float)ck[tid], w1 = (float)ck[tid + 256];
  float ss2 = w0*w0 + w1*w1;
  for (int off = 32; off > 0; off >>= 1) ss2 += __shfl_down(ss2, off);
  if ((tid & 63) == 0) red[4 + (tid >> 6)] = ss2;
  __syncthreads();
  float rk = rsqrtf((red[4]+red[5]+red[6]+red[7]) / (float)KVLR + 1e-6f);
  kvln[(size_t)s * KVLR + tid]       = (h16)(kw[tid] * w0 * rk);
  kvln[(size_t)s * KVLR + tid + 256] = (h16)(kw[tid + 256] * w1 * rk);

  if (tid < 32){
    int d = tid;
    float x = (float)ck[KVLR + 2*d];
    float y = (float)ck[KVLR + 2*d + 1];
    float a = (float)pos_ids[s] * exp2f(FREQC * (float)d);
    float cs = cosf(a), sn = sinf(a);
    cst[s*32 + d] = cs; snt[s*32 + d] = sn;
    kpe_s[d]      = (h16)(x*cs - y*sn);
    kpe_s[32 + d] = (h16)(y*cs + x*sn);
  }
  __syncthreads();
  {
    int h = tid >> 4, seg = (tid & 15) * 4;
    h16x4 o = { kpe_s[seg], kpe_s[seg+1], kpe_s[seg+2], kpe_s[seg+3] };
    *(h16x4*)&Kh[((size_t)h*S_LEN + s)*QHS + 128 + seg] = o;
  }
}

// ---------- causal flash attention (round-7 version): BM=128, BKV=64, split-KV <=8 ----------
__global__ __launch_bounds__(256, 2) void k_flash(const h16* __restrict__ Qh, const h16* __restrict__ Kh,
      const h16* __restrict__ VT, h16* __restrict__ Opart, float* __restrict__ ml){
  const int tile = 15 - blockIdx.x;   // most work first
  const int h = blockIdx.y;
  const int p = blockIdx.z;
  const int jcount = 2*tile + 2;
  const int jlo = p * 8;
  if (jlo >= jcount) return;
  const int jhi = min(jlo + 8, jcount);
  const int m0 = tile * 128;
  __shared__ __attribute__((aligned(16))) h16 Ksm[64*QHS];   // 25600 B
  __shared__ __attribute__((aligned(16))) h16 Vsm[144*64];   // 18432 B, rows 128..143 = ones
  __shared__ __attribute__((aligned(16))) h16 Psm[128*72];   // 18432 B
  const int tid = threadIdx.x, wid = tid >> 6, lane = tid & 63, quad = lane >> 4, lr = lane & 15;

  {
    h16x4 one4 = { (h16)1.f, (h16)1.f, (h16)1.f, (h16)1.f };
    *(h16x4*)&Vsm[128*64 + tid*4] = one4;
  }

  // Q fragments direct from global (once per block)
  const h16* Qbase = Qh + ((size_t)h*S_LEN + m0)*QHS;
  h16x8 qf[2][6];
#pragma unroll
  for (int rt = 0; rt < 2; rt++)
#pragma unroll
    for (int ks = 0; ks < 6; ks++)
      qf[rt][ks] = *(const h16x8*)(Qbase + (size_t)(wid*32 + rt*16 + lr)*QHS + ks*32 + quad*8);

  float mst[2][4];
  f32x4 oacc[2][9] = {};   // 8 V tiles + 1 ones tile (row-sum l)
#pragma unroll
  for (int rt = 0; rt < 2; rt++)
#pragma unroll
    for (int i = 0; i < 4; i++) mst[rt][i] = -1e30f;

  for (int j = jlo; j < jhi; ++j){
    const h16* Kg = Kh + ((size_t)h*S_LEN + j*64)*QHS;
#pragma unroll
    for (int i = 0; i < 6; i++) gld16(Kg + i*2048 + tid*8, &Ksm[i*2048 + tid*8]);
    if (tid < 64) gld16(Kg + 12288 + tid*8, &Ksm[12288 + tid*8]);
    const h16* Vg = VT + (size_t)h * VDIM * S_LEN + (size_t)j * 64;
#pragma unroll
    for (int i = 0; i < 4; i++)
      gld16(Vg + (size_t)(i*32 + (tid >> 3)) * S_LEN + (tid & 7)*8, &Vsm[i*2048 + tid*8]);
    __syncthreads();

    f32x4 sc[2][4] = {};
#pragma unroll
    for (int ks = 0; ks < 6; ks++)
#pragma unroll
      for (int ct = 0; ct < 4; ct++){
        h16x8 kf = *(const h16x8*)&Ksm[(ct*16 + lr)*QHS + ks*32 + quad*8];
        sc[0][ct] = __builtin_amdgcn_mfma_f32_16x16x32_f16(qf[0][ks], kf, sc[0][ct], 0,0,0);
        sc[1][ct] = __builtin_amdgcn_mfma_f32_16x16x32_f16(qf[1][ks], kf, sc[1][ct], 0,0,0);
      }

    if (j >= 2*tile){
#pragma unroll
      for (int rt = 0; rt < 2; rt++)
#pragma unroll
        for (int ct = 0; ct < 4; ct++){
          int kcol = j*64 + ct*16 + lr;
#pragma unroll
          for (int i = 0; i < 4; i++)
            if (kcol > m0 + wid*32 + rt*16 + quad*4 + i) sc[rt][ct][i] = -1e30f;
        }
    }

#pragma unroll
    for (int rt = 0; rt < 2; rt++){
      float al[4];
#pragma unroll
      for (int i = 0; i < 4; i++){
        float m = fmaxf(fmaxf(sc[rt][0][i], sc[rt][1][i]), fmaxf(sc[rt][2][i], sc[rt][3][i]));
#pragma unroll
        for (int off = 1; off < 16; off <<= 1) m = fmaxf(m, __shfl_xor(m, off));
        // floor guard: fully-masked rows must yield P=0, not exp(0)=1
        float mn = fmaxf(fmaxf(mst[rt][i], m), -1e29f);
        al[i] = __expf(mst[rt][i] - mn);
        mst[rt][i] = mn;
      }
#pragma unroll
      for (int ct = 0; ct < 4; ct++)
#pragma unroll
        for (int i = 0; i < 4; i++)
          Psm[(wid*32 + rt*16 + quad*4 + i)*72 + ct*16 + lr] = (h16)__expf(sc[rt][ct][i] - mst[rt][i]);
#pragma unroll
      for (int oc = 0; oc < 9; oc++)
#pragma unroll
        for (int i = 0; i < 4; i++) oacc[rt][oc][i] *= al[i];
    }

    // P rows consumed only by the wave that wrote them
#pragma unroll
    for (int ks2 = 0; ks2 < 2; ks2++){
      h16x8 pf0 = *(const h16x8*)&Psm[(wid*32 + lr)*72      + ks2*32 + quad*8];
      h16x8 pf1 = *(const h16x8*)&Psm[(wid*32 + 16 + lr)*72 + ks2*32 + quad*8];
      int cv = (ks2*32 + quad*8 + 8*(lr & 7)) & 63;
#pragma unroll
      for (int oc = 0; oc < 9; oc++){
        h16x8 vf = *(const h16x8*)&Vsm[(oc*16 + lr)*64 + cv];
        oacc[0][oc] = __builtin_amdgcn_mfma_f32_16x16x32_f16(pf0, vf, oacc[0][oc], 0,0,0);
        oacc[1][oc] = __builtin_amdgcn_mfma_f32_16x16x32_f16(pf1, vf, oacc[1][oc], 0,0,0);
      }
    }
    __syncthreads();
  }

  const int part = (tile*NHEAD + h)*4 + p;
  h16* Op = Opart + (size_t)part * 16384;
#pragma unroll
  for (int rt = 0; rt < 2; rt++){
#pragma unroll
    for (int oc = 0; oc < 8; oc++)
#pragma unroll
      for (int i = 0; i < 4; i++)
        Op[(wid*32 + rt*16 + quad*4 + i)*128 + oc*16 + lr] = (h16)oacc[rt][oc][i];
    if (lr == 0){
#pragma unroll
      for (int i = 0; i < 4; i++){
        int r = wid*32 + rt*16 + quad*4 + i;
        ml[(size_t)part*256 + r*2]     = mst[rt][i];
        ml[(size_t)part*256 + r*2 + 1] = oacc[rt][8][i];
      }
    }
  }
}

// ---------- LSE-combine partials -> Ob ----------
__global__ __launch_bounds__(256) void k_comb(const h16* __restrict__ Opart, const float* __restrict__ ml,
                                              h16* __restrict__ Ob){
  const int t = blockIdx.x, h = blockIdx.y, tid = threadIdx.x;
  const int P = (2*t + 9) >> 3;   // ceil((2t+2)/8)
  const int r = tid >> 1, c0 = (tid & 1) * 64;
  const int base = (t*NHEAD + h)*4;
  float w[4]; float M = -1e30f, denom = 0.f;
  for (int p = 0; p < P; p++) M = fmaxf(M, ml[(size_t)(base+p)*256 + r*2]);
  for (int p = 0; p < P; p++){
    w[p] = __expf(ml[(size_t)(base+p)*256 + r*2] - M);
    denom += w[p] * ml[(size_t)(base+p)*256 + r*2 + 1];
  }
  float inv = 1.f / denom;
#pragma unroll
  for (int ch = 0; ch < 8; ch++){
    float a[8] = {};
    for (int p = 0; p < P; p++){
      h16x8 v = *(const h16x8*)&Opart[(size_t)(base+p)*16384 + r*128 + c0 + ch*8];
#pragma unroll
      for (int e = 0; e < 8; e++) a[e] += w[p] * (float)v[e];
    }
    h16x8 o;
#pragma unroll
    for (int e = 0; e < 8; e++) o[e] = (h16)(a[e] * inv);
    *(h16x8*)&Ob[((size_t)(t*128 + r))*(NHEAD*VDIM) + h*VDIM + c0 + ch*8] = o;
  }
}

extern "C" void kernel_launch(void* const* d_in, const int* in_sizes, int n_in,
                              void* d_out, int out_size, void* d_ws, size_t ws_size,
                              hipStream_t stream){
  const float* hidden = (const float*)d_in[0];
  const int*   pos    = (const int*)  d_in[1];
  const float* Wqa    = (const float*)d_in[2];
  const float* qaw    = (const float*)d_in[3];
  const float* Wqb    = (const float*)d_in[4];
  const float* Wkva   = (const float*)d_in[5];
  const float* kvw    = (const float*)d_in[6];
  const float* Wkvb   = (const float*)d_in[7];
  const float* Wo     = (const float*)d_in[8];

  h16* ws = (h16*)d_ws;
  size_t off = 0;
  auto take = [&](size_t n){ h16* p = ws + off; off += n; return p; };
  h16* hb    = take(2048ull * 2048);
  h16* WoT   = take(2048ull * 2048);
  h16* Wc    = take(2176ull * 2048);   // alias region start (dead before flash)
  h16* WqbT  = take(3072ull * 1536);
  h16* WkvbT = take(4096ull * 512);
  h16* Ccomb = take(2048ull * 2176);
  h16* qln   = take(2048ull * 1536);
  h16* kvln  = take(2048ull * 512);    // alias region end
  float* cst = (float*)take(2048ull * 64);
  float* snt = (float*)take(2048ull * 64);
  h16* Qh    = take(16ull * 2048 * QHS);
  h16* Kh    = take(16ull * 2048 * QHS);
  h16* VT    = take(16ull * 128 * 2048);
  h16* Ob    = hb;                      // hb dead after Ccomb GEMM
  h16*   Opart = Wc;                    // 16*16*4*16384 h16 = 33.6 MB within 39.8 MB region
  float* mlbuf = (float*)(Wc + 16ull*16*4*16384);  // +0.5 MB, inside dead qln

  k_prep<<<7840, 256, 0, stream>>>(hidden, hb, Wqa, Wkva, Wqb, Wkvb, Wo, Wc, WqbT, WkvbT, WoT);
  k_gemm<false><<<dim3(17, 16), 256, 0, stream>>>(hb, Wc, Ccomb, 2176, 2048);
  k_norm<<<2048, 256, 0, stream>>>(Ccomb, qaw, kvw, pos, qln, kvln, Kh, cst, snt);
  k_gemm_qkv<<<dim3(56, 16), 256, 0, stream>>>(qln, WqbT, kvln, WkvbT, Qh, Kh, VT, cst, snt);
  k_flash<<<dim3(16, 16, 4), 256, 0, stream>>>(Qh, Kh, VT, Opart, mlbuf);
  k_comb<<<dim3(16, 16), 256, 0, stream>>>(Opart, mlbuf, Ob);
  k_gemm<true><<<dim3(16, 16), 256, 0, stream>>>(Ob, WoT, d_out, 2048, 2048);
}